// Round 1
// baseline (1465.689 us; speedup 1.0000x reference)
//
#include <hip/hip_runtime.h>
#include <math.h>

#define DIM 128
#define THRESH 0.1f
#define COS_EPSF 1e-8f
#define LN_EPSF 1e-5f

__device__ __forceinline__ float wred_sum(float v) {
#pragma unroll
  for (int o = 32; o > 0; o >>= 1) v += __shfl_xor(v, o);
  return v;
}
__device__ __forceinline__ float wred_max(float v) {
#pragma unroll
  for (int o = 32; o > 0; o >>= 1) v = fmaxf(v, __shfl_xor(v, o));
  return v;
}

// ---------------- CSR build ----------------
__global__ void hist_k(const int* __restrict__ row, int* __restrict__ fill, int E) {
  int e = blockIdx.x * blockDim.x + threadIdx.x;
  if (e < E) atomicAdd(&fill[row[e]], 1);
}

__global__ void scan1_k(const int* __restrict__ in, int* __restrict__ out,
                        int* __restrict__ part, int n) {
  __shared__ int sm[1024];
  int gid = blockIdx.x * 1024 + threadIdx.x;
  int v = (gid < n) ? in[gid] : 0;
  sm[threadIdx.x] = v;
  __syncthreads();
  for (int off = 1; off < 1024; off <<= 1) {
    int t = (threadIdx.x >= off) ? sm[threadIdx.x - off] : 0;
    __syncthreads();
    sm[threadIdx.x] += t;
    __syncthreads();
  }
  if (gid < n) out[gid] = sm[threadIdx.x] - v;  // exclusive
  if (threadIdx.x == 1023) part[blockIdx.x] = sm[1023];
}

__global__ void scan2_k(int* __restrict__ part, int nparts) {
  __shared__ int sm[1024];
  int v = (threadIdx.x < nparts) ? part[threadIdx.x] : 0;
  sm[threadIdx.x] = v;
  __syncthreads();
  for (int off = 1; off < 1024; off <<= 1) {
    int t = (threadIdx.x >= off) ? sm[threadIdx.x - off] : 0;
    __syncthreads();
    sm[threadIdx.x] += t;
    __syncthreads();
  }
  if (threadIdx.x < nparts) part[threadIdx.x] = sm[threadIdx.x] - v;
}

__global__ void scan3_k(int* __restrict__ out, const int* __restrict__ part, int n, int E) {
  int gid = blockIdx.x * 1024 + threadIdx.x;
  if (gid < n) out[gid] += part[blockIdx.x];
  if (gid == 0) out[n] = E;
}

__global__ void scatter_k(const int* __restrict__ row, const int* __restrict__ col,
                          const int* __restrict__ row_ptr, int* __restrict__ fill,
                          int* __restrict__ csr_col, int E) {
  int e = blockIdx.x * blockDim.x + threadIdx.x;
  if (e < E) {
    int r = row[e];
    int p = row_ptr[r] + atomicAdd(&fill[r], 1);
    csr_col[p] = col[e];
  }
}

// ---------------- per-node norms (layer 1 only; later layers fuse into epilogue) --------
__global__ void norm_k(const float* __restrict__ F, float* __restrict__ nrm, int n) {
  int wid = threadIdx.x >> 6, lane = threadIdx.x & 63;
  int r = blockIdx.x * 4 + wid;
  if (r >= n) return;
  float2 v = ((const float2*)(F + (size_t)r * DIM))[lane];
  float s = wred_sum(v.x * v.x + v.y * v.y);
  if (lane == 0) nrm[r] = fmaxf(sqrtf(s), COS_EPSF);
}

// ---------------- sims / deg / cnt pass (wave per row) ----------------
template <bool FIRST>
__global__ void sims_k(const float* __restrict__ F, const float* __restrict__ nrm,
                       const int* __restrict__ row_ptr, const int* __restrict__ csr_col,
                       float* __restrict__ s_eff, float* __restrict__ dinv,
                       int* __restrict__ cnt, int n) {
  int wid = threadIdx.x >> 6, lane = threadIdx.x & 63;
  int r = blockIdx.x * 4 + wid;
  if (r >= n) return;
  float2 fr = ((const float2*)(F + (size_t)r * DIM))[lane];
  float nr = nrm[r];
  int beg = row_ptr[r], end = row_ptr[r + 1];
  float deg = 0.f;
  for (int e = beg; e < end; ++e) {
    float se = 0.f;
    bool alive = FIRST ? true : (s_eff[e] > 0.f);
    if (alive) {
      int c = csr_col[e];
      float2 fc = ((const float2*)(F + (size_t)c * DIM))[lane];
      float d = wred_sum(fr.x * fc.x + fr.y * fc.y);
      float sims = d / (nr * nrm[c]);
      if (sims >= THRESH) {
        se = sims;
        if (lane == 0) atomicAdd(&cnt[c], 1);
      }
    }
    if (lane == 0) s_eff[e] = se;
    deg += se;  // uniform across lanes
  }
  if (lane == 0) dinv[r] = (deg > 0.f) ? (1.0f / sqrtf(deg)) : 0.f;
}

// val_self[n] = exp(1/(cnt + selfoff)); selfoff=1 layer1, 2 layers 2/3
__global__ void vself_k(const int* __restrict__ cnt, float* __restrict__ vself,
                        float selfoff, int n) {
  int i = blockIdx.x * blockDim.x + threadIdx.x;
  if (i < n) vself[i] = expf(1.0f / ((float)cnt[i] + selfoff));
}

// ---------------- dense GEMM: G[n,128] = F[n,128] @ W[128,128]  (in-place safe) --------
__global__ __launch_bounds__(256) void gemm_k(const float* F, const float* W, float* G, int n) {
  __shared__ float Ws[DIM * DIM];   // 64 KB
  __shared__ float Fs[32 * DIM];    // 16 KB
  int t = threadIdx.x;
  const float4* W4 = (const float4*)W;
  float4* Ws4 = (float4*)Ws;
#pragma unroll
  for (int j = 0; j < 16; ++j) Ws4[t + 256 * j] = W4[t + 256 * j];
  int r0 = blockIdx.x * 32;
  int rows = n - r0;
  if (rows > 32) rows = 32;
  const float4* F4 = (const float4*)(F + (size_t)r0 * DIM);
  float4* Fs4 = (float4*)Fs;
  for (int j = t; j < rows * 32; j += 256) Fs4[j] = F4[j];
  __syncthreads();
  int rr = t >> 3;
  int cg = (t & 7) * 16;
  if (rr < rows) {
    float acc[16];
#pragma unroll
    for (int j = 0; j < 16; ++j) acc[j] = 0.f;
#pragma unroll 4
    for (int k = 0; k < DIM; ++k) {
      float a = Fs[rr * DIM + k];
#pragma unroll
      for (int j = 0; j < 16; ++j) acc[j] += a * Ws[k * DIM + cg + j];
    }
    float* out = G + (size_t)(r0 + rr) * DIM + cg;
#pragma unroll
    for (int j = 0; j < 16; ++j) out[j] = acc[j];
  }
}

// ---------------- fused SpMM + bias + (LN+ReLU+norm | log_softmax) ----------------
// MODE 0: h = relu(LN(acc)); also writes nrm for the next layer's sims.
// MODE 1: out = log_softmax(acc)
template <int MODE>
__global__ void spmm_k(const float* __restrict__ G, const float* __restrict__ s_eff,
                       const float* __restrict__ dinv, const float* __restrict__ vself,
                       const int* __restrict__ row_ptr, const int* __restrict__ csr_col,
                       const float* __restrict__ bias, const float* __restrict__ gam,
                       const float* __restrict__ bet, float* __restrict__ out,
                       float* __restrict__ nrm, int n) {
  int wid = threadIdx.x >> 6, lane = threadIdx.x & 63;
  int r = blockIdx.x * 4 + wid;
  if (r >= n) return;
  float vs = vself[r];
  float2 g0 = ((const float2*)(G + (size_t)r * DIM))[lane];
  float ax = vs * g0.x, ay = vs * g0.y;
  float dr = dinv[r];
  int beg = row_ptr[r], end = row_ptr[r + 1];
  for (int e = beg; e < end; ++e) {
    float s = s_eff[e];
    if (s > 0.f) {               // uniform branch; pruned edges skip the gather
      int c = csr_col[e];
      float v = expf(dr * s * dinv[c]);
      float2 gc = ((const float2*)(G + (size_t)c * DIM))[lane];
      ax += v * gc.x;
      ay += v * gc.y;
    }
  }
  ax += bias[2 * lane];
  ay += bias[2 * lane + 1];
  if (MODE == 0) {
    float mu = wred_sum(ax + ay) * (1.0f / DIM);
    float dx = ax - mu, dy = ay - mu;
    float var = wred_sum(dx * dx + dy * dy) * (1.0f / DIM);
    float is = 1.0f / sqrtf(var + LN_EPSF);
    float hx = fmaxf(dx * is * gam[2 * lane] + bet[2 * lane], 0.f);
    float hy = fmaxf(dy * is * gam[2 * lane + 1] + bet[2 * lane + 1], 0.f);
    ((float2*)(out + (size_t)r * DIM))[lane] = make_float2(hx, hy);
    float ns = wred_sum(hx * hx + hy * hy);
    if (lane == 0) nrm[r] = fmaxf(sqrtf(ns), COS_EPSF);
  } else {
    float m = wred_max(fmaxf(ax, ay));
    float s = wred_sum(expf(ax - m) + expf(ay - m));
    float ls = logf(s) + m;
    ((float2*)(out + (size_t)r * DIM))[lane] = make_float2(ax - ls, ay - ls);
  }
}

extern "C" void kernel_launch(void* const* d_in, const int* in_sizes, int n_in,
                              void* d_out, int out_size, void* d_ws, size_t ws_size,
                              hipStream_t stream) {
  const float* x  = (const float*)d_in[0];
  const int* row  = (const int*)d_in[1];
  const int* col  = (const int*)d_in[2];
  const float* W0 = (const float*)d_in[3];
  const float* b0 = (const float*)d_in[4];
  const float* W1 = (const float*)d_in[5];
  const float* b1 = (const float*)d_in[6];
  const float* g1 = (const float*)d_in[7];
  const float* be1 = (const float*)d_in[8];
  const float* g2 = (const float*)d_in[9];
  const float* be2 = (const float*)d_in[10];
  int n = in_sizes[0] / DIM;
  int E = in_sizes[1];
  float* outp = (float*)d_out;

  char* w = (char*)d_ws;
  size_t off = 0;
  auto alloc = [&](size_t bytes) {
    char* p = w + off;
    off = (off + bytes + 255) & ~(size_t)255;
    return p;
  };
  int* row_ptr  = (int*)alloc((size_t)(n + 1) * 4);
  int* fill     = (int*)alloc((size_t)n * 4);
  int* cnt      = (int*)alloc((size_t)n * 4);
  int* part     = (int*)alloc(1024 * 4);
  float* dinv   = (float*)alloc((size_t)n * 4);
  float* vself  = (float*)alloc((size_t)n * 4);
  float* nrm    = (float*)alloc((size_t)n * 4);
  int* csr_col  = (int*)alloc((size_t)E * 4);
  float* s_eff  = (float*)alloc((size_t)E * 4);
  float* B1     = (float*)alloc((size_t)n * DIM * 4);
  (void)ws_size; (void)n_in; (void)out_size;

  int eb = (E + 255) / 256;
  int nch = (n + 1023) / 1024;
  int rb = (n + 3) / 4;      // wave-per-row kernels
  int nb = (n + 255) / 256;
  int gb = (n + 31) / 32;

  // ---- CSR build (every call: ws is re-poisoned) ----
  hipMemsetAsync(fill, 0, (size_t)n * 4, stream);
  hipLaunchKernelGGL(hist_k, dim3(eb), dim3(256), 0, stream, row, fill, E);
  hipLaunchKernelGGL(scan1_k, dim3(nch), dim3(1024), 0, stream, fill, row_ptr, part, n);
  hipLaunchKernelGGL(scan2_k, dim3(1), dim3(1024), 0, stream, part, nch);
  hipLaunchKernelGGL(scan3_k, dim3(nch), dim3(1024), 0, stream, row_ptr, part, n, E);
  hipMemsetAsync(fill, 0, (size_t)n * 4, stream);
  hipLaunchKernelGGL(scatter_k, dim3(eb), dim3(256), 0, stream, row, col, row_ptr, fill, csr_col, E);

  // ---- layer 1: feat = x ----
  hipLaunchKernelGGL(norm_k, dim3(rb), dim3(256), 0, stream, x, nrm, n);
  hipMemsetAsync(cnt, 0, (size_t)n * 4, stream);
  hipLaunchKernelGGL(sims_k<true>, dim3(rb), dim3(256), 0, stream,
                     x, nrm, row_ptr, csr_col, s_eff, dinv, cnt, n);
  hipLaunchKernelGGL(vself_k, dim3(nb), dim3(256), 0, stream, cnt, vself, 1.0f, n);
  hipLaunchKernelGGL(gemm_k, dim3(gb), dim3(256), 0, stream, x, W0, outp, n);
  hipLaunchKernelGGL(spmm_k<0>, dim3(rb), dim3(256), 0, stream,
                     outp, s_eff, dinv, vself, row_ptr, csr_col, b0, g1, be1, B1, nrm, n);

  // ---- layer 2: feat = B1 (h1) ----
  hipMemsetAsync(cnt, 0, (size_t)n * 4, stream);
  hipLaunchKernelGGL(sims_k<false>, dim3(rb), dim3(256), 0, stream,
                     B1, nrm, row_ptr, csr_col, s_eff, dinv, cnt, n);
  hipLaunchKernelGGL(vself_k, dim3(nb), dim3(256), 0, stream, cnt, vself, 2.0f, n);
  hipLaunchKernelGGL(gemm_k, dim3(gb), dim3(256), 0, stream, B1, W1, B1, n);  // in-place
  hipLaunchKernelGGL(spmm_k<0>, dim3(rb), dim3(256), 0, stream,
                     B1, s_eff, dinv, vself, row_ptr, csr_col, b1, g2, be2, outp, nrm, n);

  // ---- layer 3: feat = d_out (h2); reuses W1/b1 (source bug); log_softmax ----
  hipMemsetAsync(cnt, 0, (size_t)n * 4, stream);
  hipLaunchKernelGGL(sims_k<false>, dim3(rb), dim3(256), 0, stream,
                     outp, nrm, row_ptr, csr_col, s_eff, dinv, cnt, n);
  hipLaunchKernelGGL(vself_k, dim3(nb), dim3(256), 0, stream, cnt, vself, 2.0f, n);
  hipLaunchKernelGGL(gemm_k, dim3(gb), dim3(256), 0, stream, outp, W1, B1, n);
  hipLaunchKernelGGL(spmm_k<1>, dim3(rb), dim3(256), 0, stream,
                     B1, s_eff, dinv, vself, row_ptr, csr_col, b1, b1, b1, outp, nrm, n);
}

// Round 3
// 1231.618 us; speedup vs baseline: 1.1901x; 1.1901x over previous
//
#include <hip/hip_runtime.h>
#include <math.h>

#define DIM 128
#define THRESH 0.1f
#define COS_EPSF 1e-8f
#define LN_EPSF 1e-5f

// ---------- lane helpers ----------
__device__ __forceinline__ float red16_sum(float v) {
  v += __shfl_xor(v, 1); v += __shfl_xor(v, 2);
  v += __shfl_xor(v, 4); v += __shfl_xor(v, 8);
  return v;
}
__device__ __forceinline__ float red16_max(float v) {
  v = fmaxf(v, __shfl_xor(v, 1)); v = fmaxf(v, __shfl_xor(v, 2));
  v = fmaxf(v, __shfl_xor(v, 4)); v = fmaxf(v, __shfl_xor(v, 8));
  return v;
}
__device__ __forceinline__ float4 sh4(float4 v, int m) {
  return make_float4(__shfl_xor(v.x, m), __shfl_xor(v.y, m),
                     __shfl_xor(v.z, m), __shfl_xor(v.w, m));
}
__device__ __forceinline__ float4 add4(float4 a, float4 b) {
  return make_float4(a.x + b.x, a.y + b.y, a.z + b.z, a.w + b.w);
}

// ---------------- CSR build ----------------
__global__ void hist_k(const int* __restrict__ row, int* __restrict__ fill, int E) {
  int e = blockIdx.x * blockDim.x + threadIdx.x;
  if (e < E) atomicAdd(&fill[row[e]], 1);
}

__global__ void scan1_k(const int* __restrict__ in, int* __restrict__ out,
                        int* __restrict__ part, int n) {
  __shared__ int sm[1024];
  int gid = blockIdx.x * 1024 + threadIdx.x;
  int v = (gid < n) ? in[gid] : 0;
  sm[threadIdx.x] = v;
  __syncthreads();
  for (int off = 1; off < 1024; off <<= 1) {
    int t = (threadIdx.x >= off) ? sm[threadIdx.x - off] : 0;
    __syncthreads();
    sm[threadIdx.x] += t;
    __syncthreads();
  }
  if (gid < n) out[gid] = sm[threadIdx.x] - v;  // exclusive
  if (threadIdx.x == 1023) part[blockIdx.x] = sm[1023];
}

__global__ void scan2_k(int* __restrict__ part, int nparts) {
  __shared__ int sm[1024];
  int v = (threadIdx.x < nparts) ? part[threadIdx.x] : 0;
  sm[threadIdx.x] = v;
  __syncthreads();
  for (int off = 1; off < 1024; off <<= 1) {
    int t = (threadIdx.x >= off) ? sm[threadIdx.x - off] : 0;
    __syncthreads();
    sm[threadIdx.x] += t;
    __syncthreads();
  }
  if (threadIdx.x < nparts) part[threadIdx.x] = sm[threadIdx.x] - v;
}

// setE >= 0: also write out[n] = setE (used for CSR1 where total is known host-side)
__global__ void scan3_k(int* __restrict__ out, const int* __restrict__ part, int n, int setE) {
  int gid = blockIdx.x * 1024 + threadIdx.x;
  if (gid < n) out[gid] += part[blockIdx.x];
  if (gid == 0 && setE >= 0) out[n] = setE;
}

__global__ void fix_k(int* __restrict__ rp2, const int* __restrict__ alive, int n) {
  rp2[n] = rp2[n - 1] + alive[n - 1];
}

__global__ void scatter_k(const int* __restrict__ row, const int* __restrict__ col,
                          const int* __restrict__ row_ptr, int* __restrict__ fill,
                          int* __restrict__ csr_col, int E) {
  int e = blockIdx.x * blockDim.x + threadIdx.x;
  if (e < E) {
    int r = row[e];
    int p = row_ptr[r] + atomicAdd(&fill[r], 1);
    csr_col[p] = col[e];
  }
}

// ---------------- per-node norms of x (layer 1 only) ----------------
__global__ void norm_k(const float* __restrict__ F, float* __restrict__ nrm, int n) {
  int wid = threadIdx.x >> 6, lane = threadIdx.x & 63;
  int r = blockIdx.x * 4 + wid;
  if (r >= n) return;
  float2 v = ((const float2*)(F + (size_t)r * DIM))[lane];
  float s = v.x * v.x + v.y * v.y;
  for (int o = 32; o > 0; o >>= 1) s += __shfl_xor(s, o);
  if (lane == 0) nrm[r] = fmaxf(sqrtf(s), COS_EPSF);
}

// ---------------- sims pass: 16 lanes/edge, 4 edges per wave iteration ----------------
// FIRST: full CSR, writes s_eff + alive_cnt. else: compacted CSR2, updates s2 in place.
template <bool FIRST>
__global__ void sims_k(const float* __restrict__ F, const float* __restrict__ nrm,
                       const int* __restrict__ rp, const int* __restrict__ colA,
                       float* __restrict__ sA, float* __restrict__ dinv,
                       int* __restrict__ cnt, int* __restrict__ alive_cnt, int n) {
  int wid = threadIdx.x >> 6, lane = threadIdx.x & 63;
  int r = blockIdx.x * 4 + wid;
  if (r >= n) return;
  int sl = lane & 15, g = lane >> 4;
  const float4* Fr = (const float4*)(F + (size_t)r * DIM);
  float4 fr0 = Fr[sl * 2], fr1 = Fr[sl * 2 + 1];
  float nr = nrm[r];
  int beg = rp[r], end = rp[r + 1];
  float deg = 0.f;
  int ac = 0;
  for (int e0 = beg; e0 < end; e0 += 4) {
    int e = e0 + g;
    bool act = e < end;                       // uniform within 16-lane group
    bool alive = act;
    if (!FIRST) alive = act && (sA[e] > 0.f); // group-uniform load (same addr in group)
    float se = 0.f;
    int c = -1;
    if (alive) {
      c = colA[e];
      const float4* Fc = (const float4*)(F + (size_t)c * DIM);
      float4 c0 = Fc[sl * 2], c1 = Fc[sl * 2 + 1];
      float d = fr0.x * c0.x + fr0.y * c0.y + fr0.z * c0.z + fr0.w * c0.w +
                fr1.x * c1.x + fr1.y * c1.y + fr1.z * c1.z + fr1.w * c1.w;
      d = red16_sum(d);                       // group-uniform branch: safe shuffles
      float s = d / (nr * nrm[c]);
      if (s >= THRESH) se = s;
    }
    if (act && sl == 0) {
      sA[e] = se;
      if (se > 0.f) atomicAdd(&cnt[c], 1);
    }
    deg += se;                                // se uniform in group
    if (FIRST) ac += (se > 0.f) ? 1 : 0;
  }
  deg += __shfl_xor(deg, 16); deg += __shfl_xor(deg, 32);   // cross-group
  if (lane == 0) dinv[r] = (deg > 0.f) ? (1.0f / sqrtf(deg)) : 0.f;
  if (FIRST) {
    ac += __shfl_xor(ac, 16); ac += __shfl_xor(ac, 32);
    if (lane == 0) alive_cnt[r] = ac;
  }
}

// ---------------- compact alive edges of CSR -> CSR2 ----------------
__global__ void compact_k(const int* __restrict__ rp, const int* __restrict__ csr_col,
                          const float* __restrict__ s_eff, const int* __restrict__ rp2,
                          int* __restrict__ col2, float* __restrict__ s2, int n) {
  int wid = threadIdx.x >> 6, lane = threadIdx.x & 63;
  int r = blockIdx.x * 4 + wid;
  if (r >= n) return;
  int beg = rp[r], end = rp[r + 1];
  int base = rp2[r];
  for (int e0 = beg; e0 < end; e0 += 64) {
    int e = e0 + lane;
    float s = 0.f;
    bool a = false;
    if (e < end) { s = s_eff[e]; a = s > 0.f; }
    unsigned long long m = __ballot(a);
    int pos = base + __popcll(m & ((1ull << lane) - 1ull));
    if (a) { col2[pos] = csr_col[e]; s2[pos] = s; }
    base += __popcll(m);
  }
}

// ---------------- GEMM: G[n,128] = F[n,128] @ W[128,128] ----------------
// W column c held in 128 VGPRs per lane; F rows staged in LDS, read as broadcast.
// In-place safe (each block writes only rows it staged).
__global__ __launch_bounds__(256) void gemm_k(const float* __restrict__ F,
                                              const float* __restrict__ W,
                                              float* __restrict__ G, int n) {
  __shared__ float Fs[64 * DIM];  // 32 KB
  int t = threadIdx.x;
  int wid = t >> 6, lane = t & 63;
  int half = wid & 1, rg = wid >> 1;          // 2 col-halves x 2 row-groups
  int c = half * 64 + lane;
  float w[DIM];
#pragma unroll
  for (int k = 0; k < DIM; ++k) w[k] = W[k * DIM + c];   // coalesced across lanes

  int r0 = blockIdx.x * 64;
  int rows = n - r0; if (rows > 64) rows = 64;
  const float4* F4 = (const float4*)(F + (size_t)r0 * DIM);
  float4* Fs4 = (float4*)Fs;
  for (int i = t; i < rows * 32; i += 256) Fs4[i] = F4[i];
  __syncthreads();

  for (int rr = rg * 32; rr < rg * 32 + 32; ++rr) {
    int r = r0 + rr;
    if (r >= n) break;
    const float4* fs = (const float4*)(Fs + rr * DIM);
    float a0 = 0.f, a1 = 0.f, a2 = 0.f, a3 = 0.f;
#pragma unroll
    for (int kq = 0; kq < 32; kq += 4) {
      float4 x0 = fs[kq], x1 = fs[kq + 1], x2 = fs[kq + 2], x3 = fs[kq + 3];
      a0 += x0.x * w[4 * kq] + x0.y * w[4 * kq + 1] + x0.z * w[4 * kq + 2] + x0.w * w[4 * kq + 3];
      a1 += x1.x * w[4 * kq + 4] + x1.y * w[4 * kq + 5] + x1.z * w[4 * kq + 6] + x1.w * w[4 * kq + 7];
      a2 += x2.x * w[4 * kq + 8] + x2.y * w[4 * kq + 9] + x2.z * w[4 * kq + 10] + x2.w * w[4 * kq + 11];
      a3 += x3.x * w[4 * kq + 12] + x3.y * w[4 * kq + 13] + x3.z * w[4 * kq + 14] + x3.w * w[4 * kq + 15];
    }
    G[(size_t)r * DIM + c] = (a0 + a1) + (a2 + a3);
  }
}

// ---------------- fused SpMM (CSR2) + self term + bias + (LN+ReLU+nrm | log_softmax) ----
template <int MODE>
__global__ void spmm_k(const float* __restrict__ G, const float* __restrict__ s2,
                       const int* __restrict__ col2, const float* __restrict__ dinv,
                       const int* __restrict__ cnt, float selfoff,
                       const int* __restrict__ rp2, const float* __restrict__ bias,
                       const float* __restrict__ gam, const float* __restrict__ bet,
                       float* __restrict__ out, float* __restrict__ nrm, int n) {
  int wid = threadIdx.x >> 6, lane = threadIdx.x & 63;
  int r = blockIdx.x * 4 + wid;
  if (r >= n) return;
  int sl = lane & 15, g = lane >> 4;
  float4 a0 = make_float4(0.f, 0.f, 0.f, 0.f), a1 = a0;
  if (g == 0) {
    float vs = expf(1.0f / ((float)cnt[r] + selfoff));
    const float4* Gr = (const float4*)(G + (size_t)r * DIM);
    float4 g0 = Gr[sl * 2], g1 = Gr[sl * 2 + 1];
    a0 = make_float4(vs * g0.x, vs * g0.y, vs * g0.z, vs * g0.w);
    a1 = make_float4(vs * g1.x, vs * g1.y, vs * g1.z, vs * g1.w);
  }
  float dr = dinv[r];
  int beg = rp2[r], end = rp2[r + 1];
  for (int e0 = beg; e0 < end; e0 += 4) {
    int e = e0 + g;
    bool act = e < end;
    float s = act ? s2[e] : 0.f;              // group-uniform
    if (s > 0.f) {
      int c = col2[e];
      float v = expf(dr * s * dinv[c]);
      const float4* Gc = (const float4*)(G + (size_t)c * DIM);
      float4 c0 = Gc[sl * 2], c1 = Gc[sl * 2 + 1];
      a0 = make_float4(a0.x + v * c0.x, a0.y + v * c0.y, a0.z + v * c0.z, a0.w + v * c0.w);
      a1 = make_float4(a1.x + v * c1.x, a1.y + v * c1.y, a1.z + v * c1.z, a1.w + v * c1.w);
    }
  }
  a0 = add4(a0, sh4(a0, 16)); a0 = add4(a0, sh4(a0, 32));
  a1 = add4(a1, sh4(a1, 16)); a1 = add4(a1, sh4(a1, 32));
  const float4* B4 = (const float4*)bias;
  float4 b0 = B4[sl * 2], b1 = B4[sl * 2 + 1];
  a0 = add4(a0, b0); a1 = add4(a1, b1);
  if (MODE == 0) {
    float mu = red16_sum(a0.x + a0.y + a0.z + a0.w + a1.x + a1.y + a1.z + a1.w) * (1.0f / DIM);
    float4 d0 = make_float4(a0.x - mu, a0.y - mu, a0.z - mu, a0.w - mu);
    float4 d1 = make_float4(a1.x - mu, a1.y - mu, a1.z - mu, a1.w - mu);
    float var = red16_sum(d0.x * d0.x + d0.y * d0.y + d0.z * d0.z + d0.w * d0.w +
                          d1.x * d1.x + d1.y * d1.y + d1.z * d1.z + d1.w * d1.w) * (1.0f / DIM);
    float is = 1.0f / sqrtf(var + LN_EPSF);
    const float4* G4 = (const float4*)gam;
    const float4* Be4 = (const float4*)bet;
    float4 gm0 = G4[sl * 2], gm1 = G4[sl * 2 + 1];
    float4 be0 = Be4[sl * 2], be1 = Be4[sl * 2 + 1];
    float4 h0 = make_float4(fmaxf(d0.x * is * gm0.x + be0.x, 0.f),
                            fmaxf(d0.y * is * gm0.y + be0.y, 0.f),
                            fmaxf(d0.z * is * gm0.z + be0.z, 0.f),
                            fmaxf(d0.w * is * gm0.w + be0.w, 0.f));
    float4 h1 = make_float4(fmaxf(d1.x * is * gm1.x + be1.x, 0.f),
                            fmaxf(d1.y * is * gm1.y + be1.y, 0.f),
                            fmaxf(d1.z * is * gm1.z + be1.z, 0.f),
                            fmaxf(d1.w * is * gm1.w + be1.w, 0.f));
    if (lane < 16) {
      float4* O4 = (float4*)(out + (size_t)r * DIM);
      O4[sl * 2] = h0; O4[sl * 2 + 1] = h1;
    }
    float ns = red16_sum(h0.x * h0.x + h0.y * h0.y + h0.z * h0.z + h0.w * h0.w +
                         h1.x * h1.x + h1.y * h1.y + h1.z * h1.z + h1.w * h1.w);
    if (lane == 0) nrm[r] = fmaxf(sqrtf(ns), COS_EPSF);
  } else {
    float mx = fmaxf(fmaxf(fmaxf(a0.x, a0.y), fmaxf(a0.z, a0.w)),
                     fmaxf(fmaxf(a1.x, a1.y), fmaxf(a1.z, a1.w)));
    mx = red16_max(mx);
    float se = expf(a0.x - mx) + expf(a0.y - mx) + expf(a0.z - mx) + expf(a0.w - mx) +
               expf(a1.x - mx) + expf(a1.y - mx) + expf(a1.z - mx) + expf(a1.w - mx);
    float ls = logf(red16_sum(se)) + mx;
    if (lane < 16) {
      float4* O4 = (float4*)(out + (size_t)r * DIM);
      O4[sl * 2] = make_float4(a0.x - ls, a0.y - ls, a0.z - ls, a0.w - ls);
      O4[sl * 2 + 1] = make_float4(a1.x - ls, a1.y - ls, a1.z - ls, a1.w - ls);
    }
  }
}

extern "C" void kernel_launch(void* const* d_in, const int* in_sizes, int n_in,
                              void* d_out, int out_size, void* d_ws, size_t ws_size,
                              hipStream_t stream) {
  const float* x  = (const float*)d_in[0];
  const int* row  = (const int*)d_in[1];
  const int* col  = (const int*)d_in[2];
  const float* W0 = (const float*)d_in[3];
  const float* b0 = (const float*)d_in[4];
  const float* W1 = (const float*)d_in[5];
  const float* b1 = (const float*)d_in[6];
  const float* g1 = (const float*)d_in[7];
  const float* be1 = (const float*)d_in[8];
  const float* g2 = (const float*)d_in[9];
  const float* be2 = (const float*)d_in[10];
  int n = in_sizes[0] / DIM;
  int E = in_sizes[1];
  float* outp = (float*)d_out;

  char* w = (char*)d_ws;
  size_t off = 0;
  auto alloc = [&](size_t bytes) {
    char* p = w + off;
    off = (off + bytes + 255) & ~(size_t)255;
    return p;
  };
  int* row_ptr   = (int*)alloc((size_t)(n + 1) * 4);
  int* rp2       = (int*)alloc((size_t)(n + 1) * 4);
  int* fill      = (int*)alloc((size_t)n * 4);
  int* cnt       = (int*)alloc((size_t)n * 4);
  int* alive_cnt = (int*)alloc((size_t)n * 4);
  int* part      = (int*)alloc(1024 * 4);
  float* dinv    = (float*)alloc((size_t)n * 4);
  float* nrm     = (float*)alloc((size_t)n * 4);
  int* col2      = (int*)alloc((size_t)E * 4);
  float* s2      = (float*)alloc((size_t)E * 4);
  // Union region: full-CSR buffers (csr_col, s_eff) are dead after compact_k,
  // strictly before B1's first write (same stream) -> B1 aliases them.
  size_t mark = off;
  int* csr_col   = (int*)alloc((size_t)E * 4);
  float* s_eff   = (float*)alloc((size_t)E * 4);
  off = mark;
  float* B1      = (float*)alloc((size_t)n * DIM * 4);
  (void)ws_size; (void)n_in; (void)out_size;

  int eb = (E + 255) / 256;
  int nch = (n + 1023) / 1024;
  int rb = (n + 3) / 4;       // wave-per-row kernels
  int gb = (n + 63) / 64;     // gemm blocks

  // ---- CSR build ----
  hipMemsetAsync(fill, 0, (size_t)n * 4, stream);
  hipLaunchKernelGGL(hist_k, dim3(eb), dim3(256), 0, stream, row, fill, E);
  hipLaunchKernelGGL(scan1_k, dim3(nch), dim3(1024), 0, stream, fill, row_ptr, part, n);
  hipLaunchKernelGGL(scan2_k, dim3(1), dim3(1024), 0, stream, part, nch);
  hipLaunchKernelGGL(scan3_k, dim3(nch), dim3(1024), 0, stream, row_ptr, part, n, E);
  hipMemsetAsync(fill, 0, (size_t)n * 4, stream);
  hipLaunchKernelGGL(scatter_k, dim3(eb), dim3(256), 0, stream, row, col, row_ptr, fill, csr_col, E);

  // ---- layer 1 sims on full CSR ----
  hipLaunchKernelGGL(norm_k, dim3(rb), dim3(256), 0, stream, x, nrm, n);
  hipMemsetAsync(cnt, 0, (size_t)n * 4, stream);
  hipLaunchKernelGGL(sims_k<true>, dim3(rb), dim3(256), 0, stream,
                     x, nrm, row_ptr, csr_col, s_eff, dinv, cnt, alive_cnt, n);

  // ---- compact alive edges -> CSR2 ----
  hipLaunchKernelGGL(scan1_k, dim3(nch), dim3(1024), 0, stream, alive_cnt, rp2, part, n);
  hipLaunchKernelGGL(scan2_k, dim3(1), dim3(1024), 0, stream, part, nch);
  hipLaunchKernelGGL(scan3_k, dim3(nch), dim3(1024), 0, stream, rp2, part, n, -1);
  hipLaunchKernelGGL(fix_k, dim3(1), dim3(1), 0, stream, rp2, alive_cnt, n);
  hipLaunchKernelGGL(compact_k, dim3(rb), dim3(256), 0, stream,
                     row_ptr, csr_col, s_eff, rp2, col2, s2, n);

  // ---- layer 1: gemm + spmm ----
  hipLaunchKernelGGL(gemm_k, dim3(gb), dim3(256), 0, stream, x, W0, outp, n);
  hipLaunchKernelGGL(spmm_k<0>, dim3(rb), dim3(256), 0, stream,
                     outp, s2, col2, dinv, cnt, 1.0f, rp2, b0, g1, be1, B1, nrm, n);

  // ---- layer 2 ----
  hipMemsetAsync(cnt, 0, (size_t)n * 4, stream);
  hipLaunchKernelGGL(sims_k<false>, dim3(rb), dim3(256), 0, stream,
                     B1, nrm, rp2, col2, s2, dinv, cnt, (int*)nullptr, n);
  hipLaunchKernelGGL(gemm_k, dim3(gb), dim3(256), 0, stream, B1, W1, B1, n);  // in-place safe
  hipLaunchKernelGGL(spmm_k<0>, dim3(rb), dim3(256), 0, stream,
                     B1, s2, col2, dinv, cnt, 2.0f, rp2, b1, g2, be2, outp, nrm, n);

  // ---- layer 3 (reuses W1/b1; log_softmax) ----
  hipMemsetAsync(cnt, 0, (size_t)n * 4, stream);
  hipLaunchKernelGGL(sims_k<false>, dim3(rb), dim3(256), 0, stream,
                     outp, nrm, rp2, col2, s2, dinv, cnt, (int*)nullptr, n);
  hipLaunchKernelGGL(gemm_k, dim3(gb), dim3(256), 0, stream, outp, W1, B1, n);
  hipLaunchKernelGGL(spmm_k<1>, dim3(rb), dim3(256), 0, stream,
                     B1, s2, col2, dinv, cnt, 2.0f, rp2, b1, b1, b1, outp, nrm, n);
}

// Round 5
// 858.467 us; speedup vs baseline: 1.7073x; 1.4347x over previous
//
#include <hip/hip_runtime.h>
#include <math.h>

#define DIM 128
#define THRESH 0.1f
#define COS_EPSF 1e-8f
#define LN_EPSF 1e-5f

// ---------- lane helpers ----------
__device__ __forceinline__ float red16_sum(float v) {
  v += __shfl_xor(v, 1); v += __shfl_xor(v, 2);
  v += __shfl_xor(v, 4); v += __shfl_xor(v, 8);
  return v;
}
__device__ __forceinline__ float red16_max(float v) {
  v = fmaxf(v, __shfl_xor(v, 1)); v = fmaxf(v, __shfl_xor(v, 2));
  v = fmaxf(v, __shfl_xor(v, 4)); v = fmaxf(v, __shfl_xor(v, 8));
  return v;
}
__device__ __forceinline__ float4 sh4(float4 v, int m) {
  return make_float4(__shfl_xor(v.x, m), __shfl_xor(v.y, m),
                     __shfl_xor(v.z, m), __shfl_xor(v.w, m));
}
__device__ __forceinline__ float4 add4(float4 a, float4 b) {
  return make_float4(a.x + b.x, a.y + b.y, a.z + b.z, a.w + b.w);
}

// ---------------- CSR build ----------------
__global__ void hist_k(const int* __restrict__ row, int* __restrict__ fill, int E) {
  int e = blockIdx.x * blockDim.x + threadIdx.x;
  if (e < E) atomicAdd(&fill[row[e]], 1);
}

__global__ void scan1_k(const int* __restrict__ in, int* __restrict__ out,
                        int* __restrict__ part, int n) {
  __shared__ int sm[1024];
  int gid = blockIdx.x * 1024 + threadIdx.x;
  int v = (gid < n) ? in[gid] : 0;
  sm[threadIdx.x] = v;
  __syncthreads();
  for (int off = 1; off < 1024; off <<= 1) {
    int t = (threadIdx.x >= off) ? sm[threadIdx.x - off] : 0;
    __syncthreads();
    sm[threadIdx.x] += t;
    __syncthreads();
  }
  if (gid < n) out[gid] = sm[threadIdx.x] - v;  // exclusive
  if (threadIdx.x == 1023) part[blockIdx.x] = sm[1023];
}

__global__ void scan2_k(int* __restrict__ part, int nparts) {
  __shared__ int sm[1024];
  int v = (threadIdx.x < nparts) ? part[threadIdx.x] : 0;
  sm[threadIdx.x] = v;
  __syncthreads();
  for (int off = 1; off < 1024; off <<= 1) {
    int t = (threadIdx.x >= off) ? sm[threadIdx.x - off] : 0;
    __syncthreads();
    sm[threadIdx.x] += t;
    __syncthreads();
  }
  if (threadIdx.x < nparts) part[threadIdx.x] = sm[threadIdx.x] - v;
}

// setE >= 0: also write out[n] = setE (used for CSR1 where total is known host-side)
__global__ void scan3_k(int* __restrict__ out, const int* __restrict__ part, int n, int setE) {
  int gid = blockIdx.x * 1024 + threadIdx.x;
  if (gid < n) out[gid] += part[blockIdx.x];
  if (gid == 0 && setE >= 0) out[n] = setE;
}

__global__ void fix_k(int* __restrict__ rp2, const int* __restrict__ alive, int n) {
  rp2[n] = rp2[n - 1] + alive[n - 1];
}

__global__ void scatter_k(const int* __restrict__ row, const int* __restrict__ col,
                          const int* __restrict__ row_ptr, int* __restrict__ fill,
                          int* __restrict__ csr_col, int E) {
  int e = blockIdx.x * blockDim.x + threadIdx.x;
  if (e < E) {
    int r = row[e];
    int p = row_ptr[r] + atomicAdd(&fill[r], 1);
    csr_col[p] = col[e];
  }
}

// ---------------- per-node norms of x (layer 1 only) ----------------
__global__ void norm_k(const float* __restrict__ F, float* __restrict__ nrm, int n) {
  int wid = threadIdx.x >> 6, lane = threadIdx.x & 63;
  int r = blockIdx.x * 4 + wid;
  if (r >= n) return;
  float2 v = ((const float2*)(F + (size_t)r * DIM))[lane];
  float s = v.x * v.x + v.y * v.y;
  for (int o = 32; o > 0; o >>= 1) s += __shfl_xor(s, o);
  if (lane == 0) nrm[r] = fmaxf(sqrtf(s), COS_EPSF);
}

// ---------------- sims pass: 16 lanes/edge, 4 edges per wave iteration ----------------
// FIRST: full CSR, writes s_eff + alive_cnt. else: compacted CSR2, updates s2 in place.
template <bool FIRST>
__global__ void sims_k(const float* __restrict__ F, const float* __restrict__ nrm,
                       const int* __restrict__ rp, const int* __restrict__ colA,
                       float* __restrict__ sA, float* __restrict__ dinv,
                       int* __restrict__ cnt, int* __restrict__ alive_cnt, int n) {
  int wid = threadIdx.x >> 6, lane = threadIdx.x & 63;
  int r = blockIdx.x * 4 + wid;
  if (r >= n) return;
  int sl = lane & 15, g = lane >> 4;
  const float4* Fr = (const float4*)(F + (size_t)r * DIM);
  float4 fr0 = Fr[sl * 2], fr1 = Fr[sl * 2 + 1];
  float nr = nrm[r];
  int beg = rp[r], end = rp[r + 1];
  float deg = 0.f;
  int ac = 0;
  for (int e0 = beg; e0 < end; e0 += 4) {
    int e = e0 + g;
    bool act = e < end;                       // uniform within 16-lane group
    bool alive = act;
    if (!FIRST) alive = act && (sA[e] > 0.f); // group-uniform load (same addr in group)
    float se = 0.f;
    int c = -1;
    if (alive) {
      c = colA[e];
      const float4* Fc = (const float4*)(F + (size_t)c * DIM);
      float4 c0 = Fc[sl * 2], c1 = Fc[sl * 2 + 1];
      float d = fr0.x * c0.x + fr0.y * c0.y + fr0.z * c0.z + fr0.w * c0.w +
                fr1.x * c1.x + fr1.y * c1.y + fr1.z * c1.z + fr1.w * c1.w;
      d = red16_sum(d);                       // group-uniform branch: safe shuffles
      float s = d / (nr * nrm[c]);
      if (s >= THRESH) se = s;
    }
    if (act && sl == 0) {
      sA[e] = se;
      if (se > 0.f) atomicAdd(&cnt[c], 1);
    }
    deg += se;                                // se uniform in group
    if (FIRST) ac += (se > 0.f) ? 1 : 0;
  }
  deg += __shfl_xor(deg, 16); deg += __shfl_xor(deg, 32);   // cross-group
  if (lane == 0) dinv[r] = (deg > 0.f) ? (1.0f / sqrtf(deg)) : 0.f;
  if (FIRST) {
    ac += __shfl_xor(ac, 16); ac += __shfl_xor(ac, 32);
    if (lane == 0) alive_cnt[r] = ac;
  }
}

// ---------------- compact alive edges of CSR -> CSR2 ----------------
__global__ void compact_k(const int* __restrict__ rp, const int* __restrict__ csr_col,
                          const float* __restrict__ s_eff, const int* __restrict__ rp2,
                          int* __restrict__ col2, float* __restrict__ s2, int n) {
  int wid = threadIdx.x >> 6, lane = threadIdx.x & 63;
  int r = blockIdx.x * 4 + wid;
  if (r >= n) return;
  int beg = rp[r], end = rp[r + 1];
  int base = rp2[r];
  for (int e0 = beg; e0 < end; e0 += 64) {
    int e = e0 + lane;
    float s = 0.f;
    bool a = false;
    if (e < end) { s = s_eff[e]; a = s > 0.f; }
    unsigned long long m = __ballot(a);
    int pos = base + __popcll(m & ((1ull << lane) - 1ull));
    if (a) { col2[pos] = csr_col[e]; s2[pos] = s; }
    base += __popcll(m);
  }
}

// ---------------- GEMM: G[n,128] = F[n,128] @ W[128,128] ----------------
// 128x128 tile / block, 256 threads, 8x8 register tile per thread.
// K split in 2 phases of 64 so LDS = Fs[128][68] + Ws[64][128] = 66.8 KB -> 2 blocks/CU.
// Per-thread per k-quad: 8 F b128 + 8 W b128 per 256 FMAs (LDS-instr-bound ~31us).
// In-place safe: block writes only rows it staged.
__global__ __launch_bounds__(256, 2) void gemm_k(const float* __restrict__ F,
                                                 const float* __restrict__ W,
                                                 float* __restrict__ G, int n) {
  __shared__ float Fs[128 * 68];   // row r at r*68 (pad: +4 floats -> conflict-free reads)
  __shared__ float Ws[64 * 128];   // Ws[k_local*128 + c]
  int t = threadIdx.x;
  int tx = t & 15;                  // cols tx*4..+3 and tx*4+64..+67
  int w = t >> 6;                   // wave 0..3 -> rows 32w..32w+31
  int sub = (t >> 4) & 3;           // sub-row: thread rows = 32w + sub + 4i, i=0..7
  int r0 = blockIdx.x * 128;
  int rows = n - r0; if (rows > 128) rows = 128;

  float acc[8][8];
#pragma unroll
  for (int i = 0; i < 8; ++i)
#pragma unroll
    for (int j = 0; j < 8; ++j) acc[i][j] = 0.f;

  const float4* W4 = (const float4*)W;
  const float4* F4 = (const float4*)(F + (size_t)r0 * DIM);

  for (int p = 0; p < 2; ++p) {
    // stage W half: k = 64p..64p+63, all 128 cols (2048 float4, 8/thread)
    {
      float4* Ws4 = (float4*)Ws;
#pragma unroll
      for (int jj = 0; jj < 8; ++jj) {
        int j = t + 256 * jj;                // j = kk*32 + c4
        Ws4[j] = W4[p * 2048 + j];
      }
    }
    // stage F half: rows x 64 k (rows*16 float4)
    for (int j = t; j < rows * 16; j += 256) {
      int rr = j >> 4, kq = j & 15;
      *(float4*)(&Fs[rr * 68 + kq * 4]) = F4[rr * 32 + p * 16 + kq];
    }
    __syncthreads();

#pragma unroll 2
    for (int kq = 0; kq < 16; ++kq) {
      float4 wA[4], wB[4];
#pragma unroll
      for (int q = 0; q < 4; ++q) {
        int k = kq * 4 + q;
        wA[q] = *(const float4*)(&Ws[k * 128 + tx * 4]);
        wB[q] = *(const float4*)(&Ws[k * 128 + tx * 4 + 64]);
      }
#pragma unroll
      for (int i = 0; i < 8; ++i) {
        int rr = 32 * w + sub + 4 * i;
        float4 f = *(const float4*)(&Fs[rr * 68 + kq * 4]);
        acc[i][0] += f.x * wA[0].x + f.y * wA[1].x + f.z * wA[2].x + f.w * wA[3].x;
        acc[i][1] += f.x * wA[0].y + f.y * wA[1].y + f.z * wA[2].y + f.w * wA[3].y;
        acc[i][2] += f.x * wA[0].z + f.y * wA[1].z + f.z * wA[2].z + f.w * wA[3].z;
        acc[i][3] += f.x * wA[0].w + f.y * wA[1].w + f.z * wA[2].w + f.w * wA[3].w;
        acc[i][4] += f.x * wB[0].x + f.y * wB[1].x + f.z * wB[2].x + f.w * wB[3].x;
        acc[i][5] += f.x * wB[0].y + f.y * wB[1].y + f.z * wB[2].y + f.w * wB[3].y;
        acc[i][6] += f.x * wB[0].z + f.y * wB[1].z + f.z * wB[2].z + f.w * wB[3].z;
        acc[i][7] += f.x * wB[0].w + f.y * wB[1].w + f.z * wB[2].w + f.w * wB[3].w;
      }
    }
    __syncthreads();
  }

#pragma unroll
  for (int i = 0; i < 8; ++i) {
    int r = r0 + 32 * w + sub + 4 * i;
    if (r < n) {
      float* out = G + (size_t)r * DIM + tx * 4;
      *(float4*)out = make_float4(acc[i][0], acc[i][1], acc[i][2], acc[i][3]);
      *(float4*)(out + 64) = make_float4(acc[i][4], acc[i][5], acc[i][6], acc[i][7]);
    }
  }
}

// ---------------- fused SpMM (CSR2) + self term + bias + (LN+ReLU+nrm | log_softmax) ----
template <int MODE>
__global__ void spmm_k(const float* __restrict__ G, const float* __restrict__ s2,
                       const int* __restrict__ col2, const float* __restrict__ dinv,
                       const int* __restrict__ cnt, float selfoff,
                       const int* __restrict__ rp2, const float* __restrict__ bias,
                       const float* __restrict__ gam, const float* __restrict__ bet,
                       float* __restrict__ out, float* __restrict__ nrm, int n) {
  int wid = threadIdx.x >> 6, lane = threadIdx.x & 63;
  int r = blockIdx.x * 4 + wid;
  if (r >= n) return;
  int sl = lane & 15, g = lane >> 4;
  float4 a0 = make_float4(0.f, 0.f, 0.f, 0.f), a1 = a0;
  if (g == 0) {
    float vs = expf(1.0f / ((float)cnt[r] + selfoff));
    const float4* Gr = (const float4*)(G + (size_t)r * DIM);
    float4 g0 = Gr[sl * 2], g1 = Gr[sl * 2 + 1];
    a0 = make_float4(vs * g0.x, vs * g0.y, vs * g0.z, vs * g0.w);
    a1 = make_float4(vs * g1.x, vs * g1.y, vs * g1.z, vs * g1.w);
  }
  float dr = dinv[r];
  int beg = rp2[r], end = rp2[r + 1];
  for (int e0 = beg; e0 < end; e0 += 4) {
    int e = e0 + g;
    bool act = e < end;
    float s = act ? s2[e] : 0.f;              // group-uniform
    if (s > 0.f) {
      int c = col2[e];
      float v = expf(dr * s * dinv[c]);
      const float4* Gc = (const float4*)(G + (size_t)c * DIM);
      float4 c0 = Gc[sl * 2], c1 = Gc[sl * 2 + 1];
      a0 = make_float4(a0.x + v * c0.x, a0.y + v * c0.y, a0.z + v * c0.z, a0.w + v * c0.w);
      a1 = make_float4(a1.x + v * c1.x, a1.y + v * c1.y, a1.z + v * c1.z, a1.w + v * c1.w);
    }
  }
  a0 = add4(a0, sh4(a0, 16)); a0 = add4(a0, sh4(a0, 32));
  a1 = add4(a1, sh4(a1, 16)); a1 = add4(a1, sh4(a1, 32));
  const float4* B4 = (const float4*)bias;
  float4 b0 = B4[sl * 2], b1 = B4[sl * 2 + 1];
  a0 = add4(a0, b0); a1 = add4(a1, b1);
  if (MODE == 0) {
    float mu = red16_sum(a0.x + a0.y + a0.z + a0.w + a1.x + a1.y + a1.z + a1.w) * (1.0f / DIM);
    float4 d0 = make_float4(a0.x - mu, a0.y - mu, a0.z - mu, a0.w - mu);
    float4 d1 = make_float4(a1.x - mu, a1.y - mu, a1.z - mu, a1.w - mu);
    float var = red16_sum(d0.x * d0.x + d0.y * d0.y + d0.z * d0.z + d0.w * d0.w +
                          d1.x * d1.x + d1.y * d1.y + d1.z * d1.z + d1.w * d1.w) * (1.0f / DIM);
    float is = 1.0f / sqrtf(var + LN_EPSF);
    const float4* G4 = (const float4*)gam;
    const float4* Be4 = (const float4*)bet;
    float4 gm0 = G4[sl * 2], gm1 = G4[sl * 2 + 1];
    float4 be0 = Be4[sl * 2], be1 = Be4[sl * 2 + 1];
    float4 h0 = make_float4(fmaxf(d0.x * is * gm0.x + be0.x, 0.f),
                            fmaxf(d0.y * is * gm0.y + be0.y, 0.f),
                            fmaxf(d0.z * is * gm0.z + be0.z, 0.f),
                            fmaxf(d0.w * is * gm0.w + be0.w, 0.f));
    float4 h1 = make_float4(fmaxf(d1.x * is * gm1.x + be1.x, 0.f),
                            fmaxf(d1.y * is * gm1.y + be1.y, 0.f),
                            fmaxf(d1.z * is * gm1.z + be1.z, 0.f),
                            fmaxf(d1.w * is * gm1.w + be1.w, 0.f));
    if (lane < 16) {
      float4* O4 = (float4*)(out + (size_t)r * DIM);
      O4[sl * 2] = h0; O4[sl * 2 + 1] = h1;
    }
    float ns = red16_sum(h0.x * h0.x + h0.y * h0.y + h0.z * h0.z + h0.w * h0.w +
                         h1.x * h1.x + h1.y * h1.y + h1.z * h1.z + h1.w * h1.w);
    if (lane == 0) nrm[r] = fmaxf(sqrtf(ns), COS_EPSF);
  } else {
    float mx = fmaxf(fmaxf(fmaxf(a0.x, a0.y), fmaxf(a0.z, a0.w)),
                     fmaxf(fmaxf(a1.x, a1.y), fmaxf(a1.z, a1.w)));
    mx = red16_max(mx);
    float se = expf(a0.x - mx) + expf(a0.y - mx) + expf(a0.z - mx) + expf(a0.w - mx) +
               expf(a1.x - mx) + expf(a1.y - mx) + expf(a1.z - mx) + expf(a1.w - mx);
    float ls = logf(red16_sum(se)) + mx;
    if (lane < 16) {
      float4* O4 = (float4*)(out + (size_t)r * DIM);
      O4[sl * 2] = make_float4(a0.x - ls, a0.y - ls, a0.z - ls, a0.w - ls);
      O4[sl * 2 + 1] = make_float4(a1.x - ls, a1.y - ls, a1.z - ls, a1.w - ls);
    }
  }
}

extern "C" void kernel_launch(void* const* d_in, const int* in_sizes, int n_in,
                              void* d_out, int out_size, void* d_ws, size_t ws_size,
                              hipStream_t stream) {
  const float* x  = (const float*)d_in[0];
  const int* row  = (const int*)d_in[1];
  const int* col  = (const int*)d_in[2];
  const float* W0 = (const float*)d_in[3];
  const float* b0 = (const float*)d_in[4];
  const float* W1 = (const float*)d_in[5];
  const float* b1 = (const float*)d_in[6];
  const float* g1 = (const float*)d_in[7];
  const float* be1 = (const float*)d_in[8];
  const float* g2 = (const float*)d_in[9];
  const float* be2 = (const float*)d_in[10];
  int n = in_sizes[0] / DIM;
  int E = in_sizes[1];
  float* outp = (float*)d_out;

  char* w = (char*)d_ws;
  size_t off = 0;
  auto alloc = [&](size_t bytes) {
    char* p = w + off;
    off = (off + bytes + 255) & ~(size_t)255;
    return p;
  };
  int* row_ptr   = (int*)alloc((size_t)(n + 1) * 4);
  int* rp2       = (int*)alloc((size_t)(n + 1) * 4);
  int* fill      = (int*)alloc((size_t)n * 4);
  int* cnt       = (int*)alloc((size_t)n * 4);
  int* alive_cnt = (int*)alloc((size_t)n * 4);
  int* part      = (int*)alloc(1024 * 4);
  float* dinv    = (float*)alloc((size_t)n * 4);
  float* nrm     = (float*)alloc((size_t)n * 4);
  int* col2      = (int*)alloc((size_t)E * 4);
  float* s2      = (float*)alloc((size_t)E * 4);
  // Union region: full-CSR buffers (csr_col, s_eff) are dead after compact_k,
  // strictly before B1's first write (same stream) -> B1 aliases them.
  size_t mark = off;
  int* csr_col   = (int*)alloc((size_t)E * 4);
  float* s_eff   = (float*)alloc((size_t)E * 4);
  off = mark;
  float* B1      = (float*)alloc((size_t)n * DIM * 4);
  (void)ws_size; (void)n_in; (void)out_size;

  int eb = (E + 255) / 256;
  int nch = (n + 1023) / 1024;
  int rb = (n + 3) / 4;       // wave-per-row kernels
  int gb = (n + 127) / 128;   // gemm blocks

  // ---- CSR build ----
  hipMemsetAsync(fill, 0, (size_t)n * 4, stream);
  hipLaunchKernelGGL(hist_k, dim3(eb), dim3(256), 0, stream, row, fill, E);
  hipLaunchKernelGGL(scan1_k, dim3(nch), dim3(1024), 0, stream, fill, row_ptr, part, n);
  hipLaunchKernelGGL(scan2_k, dim3(1), dim3(1024), 0, stream, part, nch);
  hipLaunchKernelGGL(scan3_k, dim3(nch), dim3(1024), 0, stream, row_ptr, part, n, E);
  hipMemsetAsync(fill, 0, (size_t)n * 4, stream);
  hipLaunchKernelGGL(scatter_k, dim3(eb), dim3(256), 0, stream, row, col, row_ptr, fill, csr_col, E);

  // ---- layer 1 sims on full CSR ----
  hipLaunchKernelGGL(norm_k, dim3(rb), dim3(256), 0, stream, x, nrm, n);
  hipMemsetAsync(cnt, 0, (size_t)n * 4, stream);
  hipLaunchKernelGGL(sims_k<true>, dim3(rb), dim3(256), 0, stream,
                     x, nrm, row_ptr, csr_col, s_eff, dinv, cnt, alive_cnt, n);

  // ---- compact alive edges -> CSR2 ----
  hipLaunchKernelGGL(scan1_k, dim3(nch), dim3(1024), 0, stream, alive_cnt, rp2, part, n);
  hipLaunchKernelGGL(scan2_k, dim3(1), dim3(1024), 0, stream, part, nch);
  hipLaunchKernelGGL(scan3_k, dim3(nch), dim3(1024), 0, stream, rp2, part, n, -1);
  hipLaunchKernelGGL(fix_k, dim3(1), dim3(1), 0, stream, rp2, alive_cnt, n);
  hipLaunchKernelGGL(compact_k, dim3(rb), dim3(256), 0, stream,
                     row_ptr, csr_col, s_eff, rp2, col2, s2, n);

  // ---- layer 1: gemm + spmm ----
  hipLaunchKernelGGL(gemm_k, dim3(gb), dim3(256), 0, stream, x, W0, outp, n);
  hipLaunchKernelGGL(spmm_k<0>, dim3(rb), dim3(256), 0, stream,
                     outp, s2, col2, dinv, cnt, 1.0f, rp2, b0, g1, be1, B1, nrm, n);

  // ---- layer 2 ----
  hipMemsetAsync(cnt, 0, (size_t)n * 4, stream);
  hipLaunchKernelGGL(sims_k<false>, dim3(rb), dim3(256), 0, stream,
                     B1, nrm, rp2, col2, s2, dinv, cnt, (int*)nullptr, n);
  hipLaunchKernelGGL(gemm_k, dim3(gb), dim3(256), 0, stream, B1, W1, B1, n);  // in-place safe
  hipLaunchKernelGGL(spmm_k<0>, dim3(rb), dim3(256), 0, stream,
                     B1, s2, col2, dinv, cnt, 2.0f, rp2, b1, g2, be2, outp, nrm, n);

  // ---- layer 3 (reuses W1/b1; log_softmax) ----
  hipMemsetAsync(cnt, 0, (size_t)n * 4, stream);
  hipLaunchKernelGGL(sims_k<false>, dim3(rb), dim3(256), 0, stream,
                     outp, nrm, rp2, col2, s2, dinv, cnt, (int*)nullptr, n);
  hipLaunchKernelGGL(gemm_k, dim3(gb), dim3(256), 0, stream, outp, W1, B1, n);
  hipLaunchKernelGGL(spmm_k<1>, dim3(rb), dim3(256), 0, stream,
                     B1, s2, col2, dinv, cnt, 2.0f, rp2, b1, b1, b1, outp, nrm, n);
}